// Round 4
// baseline (494.528 us; speedup 1.0000x reference)
//
#include <hip/hip_runtime.h>
#include <hip/hip_bf16.h>

typedef unsigned short u16;
typedef unsigned int u32;
typedef __attribute__((ext_vector_type(8))) __bf16 bf16x8;
typedef __attribute__((ext_vector_type(4))) float f32x4;

#define B_ 64
#define N_ 64
#define FA_ 75
#define FP_ 14
#define C_ 128

// ---- static device scratch (fully rewritten every call) ----
__device__ float g_A0[4096 * 128];   // a0 branch, fp32 [row][feat]
__device__ float g_A1[4096 * 128];   // p2a-summed branch, fp32 (written by pair_fused)
__device__ float g_TB[4096 * 256];   // [T | Bo] per atom row, fp32
__device__ u16   g_Wf[208896];       // all weights in A/B-fragment layout (bf16)

// frag-weight offsets (u16 elements); layout slot = ((mt*KS+ks)*64+lane)*8+j
#define OFF_AA0   0
#define OFF_AA1   12288
#define OFF_APT   28672
#define OFF_APB   40960
#define OFF_PA0   53248
#define OFF_PA1   57344
#define OFF_AL0   73728
#define OFF_AL1   106496
#define OFF_AP1   122880
#define OFF_PP0   139264
#define OFF_PP1   143360
#define OFF_PL0T  159744
#define OFF_PL0B  176128
#define OFF_PL1   192512

__device__ __forceinline__ float bf2f(u16 a) {
    union { u32 u; float f; } v; v.u = ((u32)a) << 16; return v.f;
}
__device__ __forceinline__ u16 f2bf(float f) {
    union { float f; u32 u; } v; v.f = f;
    u32 r = v.u + 0x7fffu + ((v.u >> 16) & 1u);   // RNE
    return (u16)(r >> 16);
}
#if __has_builtin(__builtin_amdgcn_cvt_pk_bf16_f32)
__device__ __forceinline__ u32 f2bf_pk(float a, float b) {
    auto r = __builtin_amdgcn_cvt_pk_bf16_f32(a, b);
    if constexpr (sizeof(r) == 4) {
        union { decltype(r) v; u32 u; } c; c.v = r; return c.u;
    } else {
        return (u32)f2bf(a) | ((u32)f2bf(b) << 16);
    }
}
#else
__device__ __forceinline__ u32 f2bf_pk(float a, float b) {
    return (u32)f2bf(a) | ((u32)f2bf(b) << 16);
}
#endif

// per-wave input dtype detection: bf16 N(0,1) samples have sane exponents in
// the LOW halfword of each u32; fp32 mantissa bits don't. Uniform per wave.
__device__ __forceinline__ bool detect_isbf(const void* __restrict__ atom) {
    u32 wrd = ((const u32*)atom)[threadIdx.x & 63];
    u32 ex = (wrd >> 7) & 0xffu;
    unsigned long long m = __ballot(ex >= 113u && ex <= 133u);
    return __popcll(m) >= 32;
}

__device__ __forceinline__ float ldf(const void* p, size_t i, bool isbf) {
    if (isbf) return bf2f(((const u16*)p)[i]);
    return ((const float*)p)[i];
}
__device__ __forceinline__ f32x4 ldf4(const void* p, int i, bool isbf) {
    f32x4 r;
    if (isbf) {
        const u16* q = (const u16*)p + i;
        r[0] = bf2f(q[0]); r[1] = bf2f(q[1]); r[2] = bf2f(q[2]); r[3] = bf2f(q[3]);
    } else {
        r = *(const f32x4*)((const float*)p + i);
    }
    return r;
}
// pack 8 row elements k0..k0+7 (zero-padded past kmax) into bf16x8 frag word
__device__ __forceinline__ uint4 pack8(const void* p, size_t base, int kmax, int k0, bool isbf) {
    uint4 u;
    if (isbf) {
        const u16* q = (const u16*)p + base;
        u16 h[8];
#pragma unroll
        for (int j = 0; j < 8; ++j) h[j] = (k0 + j < kmax) ? q[k0 + j] : (u16)0;
        u.x = (u32)h[0] | ((u32)h[1] << 16); u.y = (u32)h[2] | ((u32)h[3] << 16);
        u.z = (u32)h[4] | ((u32)h[5] << 16); u.w = (u32)h[6] | ((u32)h[7] << 16);
    } else {
        const float* q = (const float*)p + base;
        float f[8];
#pragma unroll
        for (int j = 0; j < 8; ++j) f[j] = (k0 + j < kmax) ? q[k0 + j] : 0.f;
        u.x = f2bf_pk(f[0], f[1]); u.y = f2bf_pk(f[2], f[3]);
        u.z = f2bf_pk(f[4], f[5]); u.w = f2bf_pk(f[6], f[7]);
    }
    return u;
}

// ---------------- weight prep: global [K][128] -> A-frag layout ----------------
__global__ __launch_bounds__(256) void prep_w(
    const void* atom,
    const void* aaW0, const void* aaW1, const void* apW0,
    const void* paW0, const void* paW1, const void* alW0, const void* alW1,
    const void* apW1, const void* ppW0, const void* ppW1,
    const void* plW0, const void* plW1) {
    const bool isbf = detect_isbf(atom);
    const void* srcs[14] = {aaW0, aaW1, apW0, apW0, paW0, paW1, alW0, alW1,
                            apW1, ppW0, ppW1, plW0, plW0, plW1};
    const int Ktab[14]  = {75, 128, 75, 75, 14, 128, 256, 128, 128, 14, 128, 128, 128, 128};
    const int KStab[14] = {3, 4, 3, 3, 1, 4, 8, 4, 4, 1, 4, 4, 4, 4};
    const int rofft[14] = {0, 0, 0, 75, 0, 0, 0, 0, 0, 0, 0, 0, 128, 0};
    const int baset[14] = {OFF_AA0, OFF_AA1, OFF_APT, OFF_APB, OFF_PA0, OFF_PA1,
                           OFF_AL0, OFF_AL1, OFF_AP1, OFF_PP0, OFF_PP1,
                           OFF_PL0T, OFF_PL0B, OFF_PL1};
    int gid = blockIdx.x * 256 + threadIdx.x;
    int j = 0, s = gid;
    while (j < 14 && s >= KStab[j] * 512) { s -= KStab[j] * 512; ++j; }
    if (j >= 14) return;
    int lane = s & 63, rest = s >> 6;
    int ks = rest % KStab[j], mt = rest / KStab[j];
    int m = mt * 16 + (lane & 15), q = lane >> 4;
    float f[8];
#pragma unroll
    for (int jj = 0; jj < 8; ++jj) {
        int k = ks * 32 + q * 8 + jj;
        f[jj] = (k < Ktab[j]) ? ldf(srcs[j], (size_t)(rofft[j] + k) * 128 + m, isbf) : 0.f;
    }
    uint4 u;
    u.x = f2bf_pk(f[0], f[1]); u.y = f2bf_pk(f[2], f[3]);
    u.z = f2bf_pk(f[4], f[5]); u.w = f2bf_pk(f[6], f[7]);
    *(uint4*)&g_Wf[(size_t)baset[j] + (size_t)s * 8] = u;
}

// ---------------- MFMA GEMM cores ----------------
__device__ __forceinline__ bf16x8 as_bf(uint4 u) {
    union { uint4 u; bf16x8 b; } cv; cv.u = u; return cv.b;
}
// two-A-stripe variant (atom_pre / atom_layer, feature-partitioned waves)
template<int KS, int NT>
__device__ __forceinline__ void gemm2(const u16* __restrict__ wf,
                                      const u16* __restrict__ bF,
                                      int mt0, int lane, f32x4 (&acc)[2][NT]) {
#pragma unroll
    for (int ks = 0; ks < KS; ++ks) {
        bf16x8 a0 = *(const bf16x8*)(wf + (((mt0    ) * KS + ks) * 64 + lane) * 8);
        bf16x8 a1 = *(const bf16x8*)(wf + (((mt0 + 1) * KS + ks) * 64 + lane) * 8);
#pragma unroll
        for (int nt = 0; nt < NT; ++nt) {
            bf16x8 b = *(const bf16x8*)(bF + ((nt * KS + ks) * 64 + lane) * 8);
            acc[0][nt] = __builtin_amdgcn_mfma_f32_16x16x32_bf16(a0, b, acc[0][nt], 0, 0, 0);
            acc[1][nt] = __builtin_amdgcn_mfma_f32_16x16x32_bf16(a1, b, acc[1][nt], 0, 0, 0);
        }
    }
}
// row-partitioned variant (pair_fused): A = activations in regs, B = weights
// from g_Wf (the A-layout doubles as a valid B-frag layout: n = lane&15).
template<int KS>
__device__ __forceinline__ void gemmA(const uint4 (&af)[KS], const u16* __restrict__ wf,
                                      int lane, f32x4 (&acc)[8]) {
#pragma unroll
    for (int ks = 0; ks < KS; ++ks) {
        bf16x8 a = as_bf(af[ks]);
#pragma unroll
        for (int nt = 0; nt < 8; ++nt) {
            bf16x8 b = *(const bf16x8*)(wf + ((nt * KS + ks) * 64 + lane) * 8);
            acc[nt] = __builtin_amdgcn_mfma_f32_16x16x32_bf16(a, b, acc[nt], 0, 0, 0);
        }
    }
}
__device__ __forceinline__ void zero8(f32x4 (&a)[8]) {
#pragma unroll
    for (int t = 0; t < 8; ++t) a[t] = (f32x4){0.f, 0.f, 0.f, 0.f};
}

// ---- per-wave transpose slab helpers (XOR-swizzled, G4 pattern) ----
// slab = [16 rows][128 feats] bf16 (4KB); element (row,feat) lives at byte
//   row*256 + ((feat*2) ^ ((row&7)<<4))   -- bijective, 16B-block-preserving.
// tstore: D-frag (feat=lane&15, rows=(lane>>4)*4+r) + bias + relu -> slab
__device__ __forceinline__ void tstore(u16* S, const f32x4 (&acc)[8],
                                       const void* bias, bool isbf, int q, int c) {
#pragma unroll
    for (int t = 0; t < 8; ++t) {
        float bb = ldf(bias, t * 16 + c, isbf);
#pragma unroll
        for (int r = 0; r < 4; ++r) {
            int row = q * 4 + r;
            float x = acc[t][r] + bb;
            x = x > 0.f ? x : 0.f;
            int off = row * 256 + ((t * 32 + c * 2) ^ ((row & 7) << 4));
            *(u16*)((char*)S + off) = f2bf(x);
        }
    }
}
// tload: A-frags for row = lane&15, k-window (lane>>4)*8 within each ks
__device__ __forceinline__ void tload(const u16* S, uint4 (&af)[4], int q, int c) {
#pragma unroll
    for (int ks = 0; ks < 4; ++ks) {
        int off = c * 256 + ((ks * 64 + q * 16) ^ ((c & 7) << 4));
        af[ks] = *(const uint4*)((const char*)S + off);
    }
}

// raw barrier: drain LDS only (no cross-wave global dataflow in pair_fused)
__device__ __forceinline__ void barrier_lgkm() {
    asm volatile("s_waitcnt lgkmcnt(0)" ::: "memory");
    __builtin_amdgcn_s_barrier();
    asm volatile("" ::: "memory");
}

// C-frag -> next-layer B-frag store (one uint2 per frag per lane)
__device__ __forceinline__ void frag_store(u16* dstF, int KSd, int nt, int mt, int lane, f32x4 v) {
    int c = lane & 15, quad = lane >> 4;
    int lp = c + 16 * ((2 * mt + (quad >> 1)) & 3);
    int ks = mt >> 1;
    uint2 u; u.x = f2bf_pk(v[0], v[1]); u.y = f2bf_pk(v[2], v[3]);
    *(uint2*)(dstF + (((nt * KSd + ks) * 64 + lp) * 8 + (quad & 1) * 4)) = u;
}

__device__ __forceinline__ void store_out4(void* outp, size_t elem, f32x4 v, bool isbf) {
    if (isbf) {
        uint2 u; u.x = f2bf_pk(v[0], v[1]); u.y = f2bf_pk(v[2], v[3]);
        *(uint2*)((u16*)outp + elem) = u;
    } else {
        *(f32x4*)((float*)outp + elem) = v;
    }
}

#define EPI_RELU_STORE(ACC, BB0, BB1, DST, NTN) do {                             \
    _Pragma("unroll") for (int ii = 0; ii < 2; ++ii) {                           \
        f32x4 bb_ = ii ? (BB1) : (BB0);                                          \
        _Pragma("unroll") for (int nt_ = 0; nt_ < NTN; ++nt_) {                  \
            f32x4 v_;                                                            \
            _Pragma("unroll") for (int r_ = 0; r_ < 4; ++r_) {                   \
                float x_ = ACC[ii][nt_][r_] + bb_[r_];                           \
                v_[r_] = x_ > 0.f ? x_ : 0.f;                                    \
            }                                                                    \
            frag_store(DST, 4, nt_, mt0 + ii, lane, v_);                         \
        }                                                                        \
    }                                                                            \
} while (0)

// ---------------- Kernel: atom branch pre-work (128 blocks, 32 rows each) ---------
__global__ __launch_bounds__(256) void atom_pre(
    const void* __restrict__ atom,
    const void* __restrict__ aaB0, const void* __restrict__ aaB1) {
    __shared__ __align__(16) u16 sXF[2 * 3 * 64 * 8];   // 6KB
    __shared__ __align__(16) u16 sHF[2 * 4 * 64 * 8];   // 8KB
    const bool isbf = detect_isbf(atom);
    const int t = threadIdx.x, lane = t & 63, w = t >> 6;
    const int quad = lane >> 4;
    const int r0g = blockIdx.x * 32;
    for (int s = t; s < 2 * 3 * 64; s += 256) {
        int lane_s = s & 63, rest = s >> 6;
        int ks = rest % 3, nt = rest / 3;
        int n = nt * 16 + (lane_s & 15), q = lane_s >> 4;
        *(uint4*)&sXF[s * 8] = pack8(atom, (size_t)(r0g + n) * FA_, FA_, ks * 32 + q * 8, isbf);
    }
    __syncthreads();
    const int mt0 = 2 * w;
    {
        f32x4 bb0 = ldf4(aaB0, mt0 * 16 + quad * 4, isbf);
        f32x4 bb1 = ldf4(aaB0, (mt0 + 1) * 16 + quad * 4, isbf);
        f32x4 acc[2][2];
#pragma unroll
        for (int ii = 0; ii < 2; ++ii)
#pragma unroll
            for (int nt = 0; nt < 2; ++nt) acc[ii][nt] = (f32x4){0.f, 0.f, 0.f, 0.f};
        gemm2<3, 2>(g_Wf + OFF_AA0, sXF, mt0, lane, acc);
        EPI_RELU_STORE(acc, bb0, bb1, sHF, 2);
    }
    __syncthreads();
    {
        f32x4 bb0 = ldf4(aaB1, mt0 * 16 + quad * 4, isbf);
        f32x4 bb1 = ldf4(aaB1, (mt0 + 1) * 16 + quad * 4, isbf);
        f32x4 acc[2][2];
#pragma unroll
        for (int ii = 0; ii < 2; ++ii)
#pragma unroll
            for (int nt = 0; nt < 2; ++nt) acc[ii][nt] = (f32x4){0.f, 0.f, 0.f, 0.f};
        gemm2<4, 2>(g_Wf + OFF_AA1, sHF, mt0, lane, acc);
        int c = lane & 15;
#pragma unroll
        for (int ii = 0; ii < 2; ++ii) {
            int mt = mt0 + ii;
            f32x4 bb = ii ? bb1 : bb0;
#pragma unroll
            for (int nt = 0; nt < 2; ++nt) {
                f32x4 v;
#pragma unroll
                for (int r = 0; r < 4; ++r) { float x = acc[ii][nt][r] + bb[r]; v[r] = x > 0.f ? x : 0.f; }
                *(f32x4*)&g_A0[(size_t)(r0g + nt * 16 + c) * 128 + mt * 16 + quad * 4] = v;
            }
        }
    }
    {
        f32x4 accT[2][2], accB[2][2];
#pragma unroll
        for (int ii = 0; ii < 2; ++ii)
#pragma unroll
            for (int nt = 0; nt < 2; ++nt) { accT[ii][nt] = (f32x4){0.f,0.f,0.f,0.f}; accB[ii][nt] = (f32x4){0.f,0.f,0.f,0.f}; }
        gemm2<3, 2>(g_Wf + OFF_APT, sXF, mt0, lane, accT);
        gemm2<3, 2>(g_Wf + OFF_APB, sXF, mt0, lane, accB);
        int c = lane & 15;
#pragma unroll
        for (int ii = 0; ii < 2; ++ii) {
            int mt = mt0 + ii;
#pragma unroll
            for (int nt = 0; nt < 2; ++nt) {
                size_t row = (size_t)(r0g + nt * 16 + c);
                *(f32x4*)&g_TB[row * 256 + mt * 16 + quad * 4] = accT[ii][nt];
                *(f32x4*)&g_TB[row * 256 + 128 + mt * 16 + quad * 4] = accB[ii][nt];
            }
        }
    }
}

// ---------------- Kernel: atom_layer (256 blocks, 16 rows each) -------------------
__global__ __launch_bounds__(256) void atom_layer(
    const void* __restrict__ atom,
    const void* __restrict__ alB0, const void* __restrict__ alB1,
    void* __restrict__ out) {
    __shared__ __align__(16) u16 sXF[1 * 8 * 64 * 8];   // 8KB
    __shared__ __align__(16) u16 sHF[1 * 4 * 64 * 8];   // 4KB
    const bool isbf = detect_isbf(atom);
    const int t = threadIdx.x, lane = t & 63, w = t >> 6;
    const int quad = lane >> 4;
    const int r0g = blockIdx.x * 16;
    for (int s = t; s < 8 * 64; s += 256) {
        int lane_s = s & 63, ks = s >> 6;
        int n = lane_s & 15, q = lane_s >> 4;
        int k0 = ks * 32 + q * 8;
        const float* src = (k0 < 128) ? &g_A0[(size_t)(r0g + n) * 128 + k0]
                                      : &g_A1[(size_t)(r0g + n) * 128 + (k0 - 128)];
        f32x4 f0 = *(const f32x4*)src, f1 = *(const f32x4*)(src + 4);
        uint4 u;
        u.x = f2bf_pk(f0[0], f0[1]); u.y = f2bf_pk(f0[2], f0[3]);
        u.z = f2bf_pk(f1[0], f1[1]); u.w = f2bf_pk(f1[2], f1[3]);
        *(uint4*)&sXF[s * 8] = u;
    }
    __syncthreads();
    const int mt0 = 2 * w;
    {
        f32x4 bb0 = ldf4(alB0, mt0 * 16 + quad * 4, isbf);
        f32x4 bb1 = ldf4(alB0, (mt0 + 1) * 16 + quad * 4, isbf);
        f32x4 acc[2][1];
#pragma unroll
        for (int ii = 0; ii < 2; ++ii) acc[ii][0] = (f32x4){0.f, 0.f, 0.f, 0.f};
        gemm2<8, 1>(g_Wf + OFF_AL0, sXF, mt0, lane, acc);
        EPI_RELU_STORE(acc, bb0, bb1, sHF, 1);
    }
    __syncthreads();
    {
        f32x4 bb0 = ldf4(alB1, mt0 * 16 + quad * 4, isbf);
        f32x4 bb1 = ldf4(alB1, (mt0 + 1) * 16 + quad * 4, isbf);
        f32x4 acc[2][1];
#pragma unroll
        for (int ii = 0; ii < 2; ++ii) acc[ii][0] = (f32x4){0.f, 0.f, 0.f, 0.f};
        gemm2<4, 1>(g_Wf + OFF_AL1, sHF, mt0, lane, acc);
        int c = lane & 15;
#pragma unroll
        for (int ii = 0; ii < 2; ++ii) {
            int mt = mt0 + ii;
            f32x4 bb = ii ? bb1 : bb0;
            f32x4 v;
#pragma unroll
            for (int r = 0; r < 4; ++r) { float x = acc[ii][0][r] + bb[r]; v[r] = x > 0.f ? x : 0.f; }
            store_out4(out, (size_t)(r0g + c) * 128 + mt * 16 + quad * 4, v, isbf);
        }
    }
}

// ---------------- Kernel: row-partitioned fused pair branch (4096 blocks) ---------
// 4 waves x 16 pair-rows each; every wave computes ALL 128 features of its rows,
// so the whole 6-layer chain is wave-local: ZERO block barriers until the final
// PairToAtom cross-wave reduction. Inter-layer transpose via per-wave 4KB
// XOR-swizzled LDS slabs. Weights are consumed as B-frags straight from g_Wf.
__global__ __launch_bounds__(256, 3) void pair_fused(
    const void* __restrict__ atom,
    const void* __restrict__ pairx,
    const void* __restrict__ apB0, const void* __restrict__ apB1,
    const void* __restrict__ ppB0, const void* __restrict__ ppB1,
    const void* __restrict__ plB0, const void* __restrict__ plB1,
    const void* __restrict__ paB0, const void* __restrict__ paB1,
    void* __restrict__ out) {
    __shared__ __align__(16) u16 sT[4][3][2048];   // 48KB: 3 slabs per wave
    __shared__ float sRed[4][128];                 // 2KB: PairToAtom partials
    const bool isbf = detect_isbf(atom);
    const int t = threadIdx.x, lane = t & 63, w = t >> 6;
    const int q = lane >> 4, c = lane & 15;
    const int bx = blockIdx.x;
    const int b = bx >> 6, i = bx & 63;
    const int trow = b * 64;
    const size_t prow0 = (size_t)b * 4096 + (size_t)i * 64;
    const int rb = w * 16;                         // wave's local row base
    u16* S0 = &sT[w][0][0];
    u16* S1 = &sT[w][1][0];
    u16* S2 = &sT[w][2][0];

    // ---- stage: H0/H1 A-frags built directly in registers ----
    // H0[j][k] = relu(T[i][k] + Bo[j][k] + b0[k]) ; H1[j][k] = relu(T[j][k] + Bo[i][k] + b0[k])
    uint4 H0f[4], H1f[4];
    {
        const float* TBi = &g_TB[(size_t)(trow + i) * 256];
        const float* TBr = &g_TB[(size_t)(trow + rb + c) * 256];
#pragma unroll
        for (int ks = 0; ks < 4; ++ks) {
            int k0 = ks * 32 + q * 8;
            f32x4 ti0 = *(const f32x4*)(TBi + k0),       ti1 = *(const f32x4*)(TBi + k0 + 4);
            f32x4 bi0 = *(const f32x4*)(TBi + 128 + k0), bi1 = *(const f32x4*)(TBi + 132 + k0);
            f32x4 tr0 = *(const f32x4*)(TBr + k0),       tr1 = *(const f32x4*)(TBr + k0 + 4);
            f32x4 br0 = *(const f32x4*)(TBr + 128 + k0), br1 = *(const f32x4*)(TBr + 132 + k0);
            f32x4 b0a = ldf4(apB0, k0, isbf), b0b = ldf4(apB0, k0 + 4, isbf);
            float h0[8], h1[8];
#pragma unroll
            for (int r = 0; r < 4; ++r) {
                float x0 = ti0[r] + b0a[r] + br0[r]; h0[r]     = x0 > 0.f ? x0 : 0.f;
                float x1 = ti1[r] + b0b[r] + br1[r]; h0[4 + r] = x1 > 0.f ? x1 : 0.f;
                float y0 = tr0[r] + bi0[r] + b0a[r]; h1[r]     = y0 > 0.f ? y0 : 0.f;
                float y1 = tr1[r] + bi1[r] + b0b[r]; h1[4 + r] = y1 > 0.f ? y1 : 0.f;
            }
            uint4 u0, u1;
            u0.x = f2bf_pk(h0[0], h0[1]); u0.y = f2bf_pk(h0[2], h0[3]);
            u0.z = f2bf_pk(h0[4], h0[5]); u0.w = f2bf_pk(h0[6], h0[7]);
            u1.x = f2bf_pk(h1[0], h1[1]); u1.y = f2bf_pk(h1[2], h1[3]);
            u1.z = f2bf_pk(h1[4], h1[5]); u1.w = f2bf_pk(h1[6], h1[7]);
            H0f[ks] = u0; H1f[ks] = u1;
        }
    }
    // pair_x A-frag (K=14 padded to 32, single ks)
    uint4 Prf[1];
    Prf[0] = pack8(pairx, (prow0 + rb + c) * FP_, FP_, q * 8, isbf);

    // ---- C: P0 = relu(H0@apW1+b1) + relu(H1@apW1+b1) -> S0 ----
    {
        f32x4 aA[8], aB[8];
        zero8(aA); zero8(aB);
        gemmA<4>(H0f, g_Wf + OFF_AP1, lane, aA);
        gemmA<4>(H1f, g_Wf + OFF_AP1, lane, aB);
#pragma unroll
        for (int tt = 0; tt < 8; ++tt) {
            float bb = ldf(apB1, tt * 16 + c, isbf);
#pragma unroll
            for (int r = 0; r < 4; ++r) {
                int row = q * 4 + r;
                float x = aA[tt][r] + bb; x = x > 0.f ? x : 0.f;
                float y = aB[tt][r] + bb; y = y > 0.f ? y : 0.f;
                int off = row * 256 + ((tt * 32 + c * 2) ^ ((row & 7) << 4));
                *(u16*)((char*)S0 + off) = f2bf(x + y);
            }
        }
    }
    // ---- Hp = relu(Pr@ppW0+b0p) -> S1 ; HpA = relu(Pr@paW0+b0pa) -> S2 ----
    {
        f32x4 acc[8];
        zero8(acc);
        gemmA<1>(Prf, g_Wf + OFF_PP0, lane, acc);
        tstore(S1, acc, ppB0, isbf, q, c);
        zero8(acc);
        gemmA<1>(Prf, g_Wf + OFF_PA0, lane, acc);
        tstore(S2, acc, paB0, isbf, q, c);
    }
    // ---- D: C3 = P0 @ plW0_top (held in regs) ----
    f32x4 C3[8];
    uint4 af[4];
    zero8(C3);
    tload(S0, af, q, c);
    gemmA<4>(af, g_Wf + OFF_PL0T, lane, C3);
    // ---- E: P1 = relu(Hp@ppW1+b1p) -> S0 ; A1 = rowsum(relu(HpA@paW1+b1pa)) ----
    {
        f32x4 acc[8];
        tload(S1, af, q, c);
        zero8(acc);
        gemmA<4>(af, g_Wf + OFF_PP1, lane, acc);
        tstore(S0, acc, ppB1, isbf, q, c);
        tload(S2, af, q, c);
        zero8(acc);
        gemmA<4>(af, g_Wf + OFF_PA1, lane, acc);
        float s[8];
#pragma unroll
        for (int tt = 0; tt < 8; ++tt) {
            float bb = ldf(paB1, tt * 16 + c, isbf);
            float sv = 0.f;
#pragma unroll
            for (int r = 0; r < 4; ++r) {
                float x = acc[tt][r] + bb;
                sv += (x > 0.f ? x : 0.f);
            }
            s[tt] = sv;
        }
#pragma unroll
        for (int tt = 0; tt < 8; ++tt) {
            s[tt] += __shfl_xor(s[tt], 16, 64);
            s[tt] += __shfl_xor(s[tt], 32, 64);
        }
        if (lane < 16) {
#pragma unroll
            for (int tt = 0; tt < 8; ++tt) sRed[w][tt * 16 + lane] = s[tt];
        }
    }
    // ---- F: C3 += P1 @ plW0_bot ; Hl = relu(C3 + b0l) -> S1 ----
    tload(S0, af, q, c);
    gemmA<4>(af, g_Wf + OFF_PL0B, lane, C3);
    tstore(S1, C3, plB0, isbf, q, c);
    // ---- G: out = relu(Hl@plW1 + b1l) ----
    {
        f32x4 acc[8];
        tload(S1, af, q, c);
        zero8(acc);
        gemmA<4>(af, g_Wf + OFF_PL1, lane, acc);
        const size_t NA = (size_t)B_ * N_ * C_;   // 524288
#pragma unroll
        for (int tt = 0; tt < 8; ++tt) {
            float bb = ldf(plB1, tt * 16 + c, isbf);
#pragma unroll
            for (int r = 0; r < 4; ++r) {
                int row = q * 4 + r;
                float x = acc[tt][r] + bb; x = x > 0.f ? x : 0.f;
                size_t e = NA + (prow0 + rb + row) * 128 + tt * 16 + c;
                if (isbf) ((u16*)out)[e] = f2bf(x);
                else      ((float*)out)[e] = x;
            }
        }
    }
    // ---- single block barrier: combine the 4 waves' PairToAtom partials ----
    barrier_lgkm();
    if (t < 128) {
        float v = sRed[0][t] + sRed[1][t] + sRed[2][t] + sRed[3][t];
        g_A1[(size_t)bx * 128 + t] = v;
    }
}

extern "C" void kernel_launch(void* const* d_in, const int* in_sizes, int n_in,
                              void* d_out, int out_size, void* d_ws, size_t ws_size,
                              hipStream_t stream) {
    const void* atom  = d_in[0];
    const void* pairx = d_in[1];
    const void* aaW0 = d_in[2];  const void* aaB0 = d_in[3];
    const void* aaW1 = d_in[4];  const void* aaB1 = d_in[5];
    const void* paW0 = d_in[6];  const void* paB0 = d_in[7];
    const void* paW1 = d_in[8];  const void* paB1 = d_in[9];
    const void* alW0 = d_in[10]; const void* alB0 = d_in[11];
    const void* alW1 = d_in[12]; const void* alB1 = d_in[13];
    const void* apW0 = d_in[14]; const void* apB0 = d_in[15];
    const void* apW1 = d_in[16]; const void* apB1 = d_in[17];
    const void* ppW0 = d_in[18]; const void* ppB0 = d_in[19];
    const void* ppW1 = d_in[20]; const void* ppB1 = d_in[21];
    const void* plW0 = d_in[22]; const void* plB0 = d_in[23];
    const void* plW1 = d_in[24]; const void* plB1 = d_in[25];
    (void)d_ws; (void)ws_size; (void)in_sizes; (void)n_in; (void)out_size;

    prep_w<<<102, 256, 0, stream>>>(atom, aaW0, aaW1, apW0, paW0, paW1, alW0, alW1,
                                    apW1, ppW0, ppW1, plW0, plW1);
    atom_pre<<<128, 256, 0, stream>>>(atom, aaB0, aaB1);
    pair_fused<<<4096, 256, 0, stream>>>(atom, pairx, apB0, apB1, ppB0, ppB1,
                                         plB0, plB1, paB0, paB1, d_out);
    atom_layer<<<256, 256, 0, stream>>>(atom, alB0, alB1, d_out);
}

// Round 5
// 326.308 us; speedup vs baseline: 1.5155x; 1.5155x over previous
//
#include <hip/hip_runtime.h>
#include <hip/hip_bf16.h>

typedef unsigned short u16;
typedef unsigned int u32;
typedef __attribute__((ext_vector_type(8))) __bf16 bf16x8;
typedef __attribute__((ext_vector_type(4))) float f32x4;

#define B_ 64
#define N_ 64
#define FA_ 75
#define FP_ 14
#define C_ 128

// ---- static device scratch (fully rewritten every call) ----
__device__ float g_A0[4096 * 128];   // a0 branch, fp32 [row][feat]
__device__ float g_A1[8192 * 128];   // p2a 32-row partial sums, fp32 (two per atom row)
__device__ float g_TB[4096 * 256];   // [T | Bo] per atom row, fp32
__device__ u16   g_Wf[208896];       // all weights in A-fragment layout (bf16)

// frag-weight offsets (u16 elements); layout slot = ((mt*KS+ks)*64+lane)*8+j
#define OFF_AA0   0
#define OFF_AA1   12288
#define OFF_APT   28672
#define OFF_APB   40960
#define OFF_PA0   53248
#define OFF_PA1   57344
#define OFF_AL0   73728
#define OFF_AL1   106496
#define OFF_AP1   122880
#define OFF_PP0   139264
#define OFF_PP1   143360
#define OFF_PL0T  159744
#define OFF_PL0B  176128
#define OFF_PL1   192512

__device__ __forceinline__ float bf2f(u16 a) {
    union { u32 u; float f; } v; v.u = ((u32)a) << 16; return v.f;
}
__device__ __forceinline__ u16 f2bf(float f) {
    union { float f; u32 u; } v; v.f = f;
    u32 r = v.u + 0x7fffu + ((v.u >> 16) & 1u);   // RNE
    return (u16)(r >> 16);
}
#if __has_builtin(__builtin_amdgcn_cvt_pk_bf16_f32)
__device__ __forceinline__ u32 f2bf_pk(float a, float b) {
    auto r = __builtin_amdgcn_cvt_pk_bf16_f32(a, b);
    if constexpr (sizeof(r) == 4) {
        union { decltype(r) v; u32 u; } c; c.v = r; return c.u;
    } else {
        return (u32)f2bf(a) | ((u32)f2bf(b) << 16);
    }
}
#else
__device__ __forceinline__ u32 f2bf_pk(float a, float b) {
    return (u32)f2bf(a) | ((u32)f2bf(b) << 16);
}
#endif

// per-wave input dtype detection: bf16 N(0,1) samples have sane exponents in
// the LOW halfword of each u32; fp32 mantissa bits don't. Uniform per wave.
__device__ __forceinline__ bool detect_isbf(const void* __restrict__ atom) {
    u32 wrd = ((const u32*)atom)[threadIdx.x & 63];
    u32 ex = (wrd >> 7) & 0xffu;
    unsigned long long m = __ballot(ex >= 113u && ex <= 133u);
    return __popcll(m) >= 32;
}

__device__ __forceinline__ float ldf(const void* p, size_t i, bool isbf) {
    if (isbf) return bf2f(((const u16*)p)[i]);
    return ((const float*)p)[i];
}
__device__ __forceinline__ f32x4 ldf4(const void* p, int i, bool isbf) {
    f32x4 r;
    if (isbf) {
        const u16* q = (const u16*)p + i;
        r[0] = bf2f(q[0]); r[1] = bf2f(q[1]); r[2] = bf2f(q[2]); r[3] = bf2f(q[3]);
    } else {
        r = *(const f32x4*)((const float*)p + i);
    }
    return r;
}
// pack 8 row elements k0..k0+7 (zero-padded past kmax) into bf16x8 frag word
__device__ __forceinline__ uint4 pack8(const void* p, size_t base, int kmax, int k0, bool isbf) {
    uint4 u;
    if (isbf) {
        const u16* q = (const u16*)p + base;
        u16 h[8];
#pragma unroll
        for (int j = 0; j < 8; ++j) h[j] = (k0 + j < kmax) ? q[k0 + j] : (u16)0;
        u.x = (u32)h[0] | ((u32)h[1] << 16); u.y = (u32)h[2] | ((u32)h[3] << 16);
        u.z = (u32)h[4] | ((u32)h[5] << 16); u.w = (u32)h[6] | ((u32)h[7] << 16);
    } else {
        const float* q = (const float*)p + base;
        float f[8];
#pragma unroll
        for (int j = 0; j < 8; ++j) f[j] = (k0 + j < kmax) ? q[k0 + j] : 0.f;
        u.x = f2bf_pk(f[0], f[1]); u.y = f2bf_pk(f[2], f[3]);
        u.z = f2bf_pk(f[4], f[5]); u.w = f2bf_pk(f[6], f[7]);
    }
    return u;
}

// ---------------- weight prep: global [K][128] -> A-frag layout ----------------
__global__ __launch_bounds__(256) void prep_w(
    const void* atom,
    const void* aaW0, const void* aaW1, const void* apW0,
    const void* paW0, const void* paW1, const void* alW0, const void* alW1,
    const void* apW1, const void* ppW0, const void* ppW1,
    const void* plW0, const void* plW1) {
    const bool isbf = detect_isbf(atom);
    const void* srcs[14] = {aaW0, aaW1, apW0, apW0, paW0, paW1, alW0, alW1,
                            apW1, ppW0, ppW1, plW0, plW0, plW1};
    const int Ktab[14]  = {75, 128, 75, 75, 14, 128, 256, 128, 128, 14, 128, 128, 128, 128};
    const int KStab[14] = {3, 4, 3, 3, 1, 4, 8, 4, 4, 1, 4, 4, 4, 4};
    const int rofft[14] = {0, 0, 0, 75, 0, 0, 0, 0, 0, 0, 0, 0, 128, 0};
    const int baset[14] = {OFF_AA0, OFF_AA1, OFF_APT, OFF_APB, OFF_PA0, OFF_PA1,
                           OFF_AL0, OFF_AL1, OFF_AP1, OFF_PP0, OFF_PP1,
                           OFF_PL0T, OFF_PL0B, OFF_PL1};
    int gid = blockIdx.x * 256 + threadIdx.x;
    int j = 0, s = gid;
    while (j < 14 && s >= KStab[j] * 512) { s -= KStab[j] * 512; ++j; }
    if (j >= 14) return;
    int lane = s & 63, rest = s >> 6;
    int ks = rest % KStab[j], mt = rest / KStab[j];
    int m = mt * 16 + (lane & 15), q = lane >> 4;
    float f[8];
#pragma unroll
    for (int jj = 0; jj < 8; ++jj) {
        int k = ks * 32 + q * 8 + jj;
        f[jj] = (k < Ktab[j]) ? ldf(srcs[j], (size_t)(rofft[j] + k) * 128 + m, isbf) : 0.f;
    }
    uint4 u;
    u.x = f2bf_pk(f[0], f[1]); u.y = f2bf_pk(f[2], f[3]);
    u.z = f2bf_pk(f[4], f[5]); u.w = f2bf_pk(f[6], f[7]);
    *(uint4*)&g_Wf[(size_t)baset[j] + (size_t)s * 8] = u;
}

// ---------------- MFMA GEMM core ----------------
template<int KS, int NT>
__device__ __forceinline__ void gemm2(const u16* __restrict__ wf,
                                      const u16* __restrict__ bF,
                                      int mt0, int lane, f32x4 (&acc)[2][NT]) {
#pragma unroll
    for (int ks = 0; ks < KS; ++ks) {
        bf16x8 a0 = *(const bf16x8*)(wf + (((mt0    ) * KS + ks) * 64 + lane) * 8);
        bf16x8 a1 = *(const bf16x8*)(wf + (((mt0 + 1) * KS + ks) * 64 + lane) * 8);
#pragma unroll
        for (int nt = 0; nt < NT; ++nt) {
            bf16x8 b = *(const bf16x8*)(bF + ((nt * KS + ks) * 64 + lane) * 8);
            acc[0][nt] = __builtin_amdgcn_mfma_f32_16x16x32_bf16(a0, b, acc[0][nt], 0, 0, 0);
            acc[1][nt] = __builtin_amdgcn_mfma_f32_16x16x32_bf16(a1, b, acc[1][nt], 0, 0, 0);
        }
    }
}

// C-frag -> next-layer B-frag store (one uint2 per frag per lane)
__device__ __forceinline__ void frag_store(u16* dstF, int KSd, int nt, int mt, int lane, f32x4 v) {
    int c = lane & 15, quad = lane >> 4;
    int lp = c + 16 * ((2 * mt + (quad >> 1)) & 3);
    int ks = mt >> 1;
    uint2 u; u.x = f2bf_pk(v[0], v[1]); u.y = f2bf_pk(v[2], v[3]);
    *(uint2*)(dstF + (((nt * KSd + ks) * 64 + lp) * 8 + (quad & 1) * 4)) = u;
}

__device__ __forceinline__ void store_out4(void* outp, size_t elem, f32x4 v, bool isbf) {
    if (isbf) {
        uint2 u; u.x = f2bf_pk(v[0], v[1]); u.y = f2bf_pk(v[2], v[3]);
        *(uint2*)((u16*)outp + elem) = u;
    } else {
        *(f32x4*)((float*)outp + elem) = v;
    }
}

#define EPI_RELU_STORE(ACC, BB0, BB1, DST, NTN) do {                             \
    _Pragma("unroll") for (int ii = 0; ii < 2; ++ii) {                           \
        f32x4 bb_ = ii ? (BB1) : (BB0);                                          \
        _Pragma("unroll") for (int nt_ = 0; nt_ < NTN; ++nt_) {                  \
            f32x4 v_;                                                            \
            _Pragma("unroll") for (int r_ = 0; r_ < 4; ++r_) {                   \
                float x_ = ACC[ii][nt_][r_] + bb_[r_];                           \
                v_[r_] = x_ > 0.f ? x_ : 0.f;                                    \
            }                                                                    \
            frag_store(DST, 4, nt_, mt0 + ii, lane, v_);                         \
        }                                                                        \
    }                                                                            \
} while (0)

// ---------------- Kernel: atom branch pre-work (128 blocks, 32 rows each) ---------
__global__ __launch_bounds__(256) void atom_pre(
    const void* __restrict__ atom,
    const void* __restrict__ aaB0, const void* __restrict__ aaB1) {
    __shared__ __align__(16) u16 sXF[2 * 3 * 64 * 8];   // 6KB
    __shared__ __align__(16) u16 sHF[2 * 4 * 64 * 8];   // 8KB
    const bool isbf = detect_isbf(atom);
    const int t = threadIdx.x, lane = t & 63, w = t >> 6;
    const int quad = lane >> 4;
    const int r0g = blockIdx.x * 32;
    for (int s = t; s < 2 * 3 * 64; s += 256) {
        int lane_s = s & 63, rest = s >> 6;
        int ks = rest % 3, nt = rest / 3;
        int n = nt * 16 + (lane_s & 15), q = lane_s >> 4;
        *(uint4*)&sXF[s * 8] = pack8(atom, (size_t)(r0g + n) * FA_, FA_, ks * 32 + q * 8, isbf);
    }
    __syncthreads();
    const int mt0 = 2 * w;
    {
        f32x4 bb0 = ldf4(aaB0, mt0 * 16 + quad * 4, isbf);
        f32x4 bb1 = ldf4(aaB0, (mt0 + 1) * 16 + quad * 4, isbf);
        f32x4 acc[2][2];
#pragma unroll
        for (int ii = 0; ii < 2; ++ii)
#pragma unroll
            for (int nt = 0; nt < 2; ++nt) acc[ii][nt] = (f32x4){0.f, 0.f, 0.f, 0.f};
        gemm2<3, 2>(g_Wf + OFF_AA0, sXF, mt0, lane, acc);
        EPI_RELU_STORE(acc, bb0, bb1, sHF, 2);
    }
    __syncthreads();
    {
        f32x4 bb0 = ldf4(aaB1, mt0 * 16 + quad * 4, isbf);
        f32x4 bb1 = ldf4(aaB1, (mt0 + 1) * 16 + quad * 4, isbf);
        f32x4 acc[2][2];
#pragma unroll
        for (int ii = 0; ii < 2; ++ii)
#pragma unroll
            for (int nt = 0; nt < 2; ++nt) acc[ii][nt] = (f32x4){0.f, 0.f, 0.f, 0.f};
        gemm2<4, 2>(g_Wf + OFF_AA1, sHF, mt0, lane, acc);
        int c = lane & 15;
#pragma unroll
        for (int ii = 0; ii < 2; ++ii) {
            int mt = mt0 + ii;
            f32x4 bb = ii ? bb1 : bb0;
#pragma unroll
            for (int nt = 0; nt < 2; ++nt) {
                f32x4 v;
#pragma unroll
                for (int r = 0; r < 4; ++r) { float x = acc[ii][nt][r] + bb[r]; v[r] = x > 0.f ? x : 0.f; }
                *(f32x4*)&g_A0[(size_t)(r0g + nt * 16 + c) * 128 + mt * 16 + quad * 4] = v;
            }
        }
    }
    {
        f32x4 accT[2][2], accB[2][2];
#pragma unroll
        for (int ii = 0; ii < 2; ++ii)
#pragma unroll
            for (int nt = 0; nt < 2; ++nt) { accT[ii][nt] = (f32x4){0.f,0.f,0.f,0.f}; accB[ii][nt] = (f32x4){0.f,0.f,0.f,0.f}; }
        gemm2<3, 2>(g_Wf + OFF_APT, sXF, mt0, lane, accT);
        gemm2<3, 2>(g_Wf + OFF_APB, sXF, mt0, lane, accB);
        int c = lane & 15;
#pragma unroll
        for (int ii = 0; ii < 2; ++ii) {
            int mt = mt0 + ii;
#pragma unroll
            for (int nt = 0; nt < 2; ++nt) {
                size_t row = (size_t)(r0g + nt * 16 + c);
                *(f32x4*)&g_TB[row * 256 + mt * 16 + quad * 4] = accT[ii][nt];
                *(f32x4*)&g_TB[row * 256 + 128 + mt * 16 + quad * 4] = accB[ii][nt];
            }
        }
    }
}

// ---------------- Kernel: atom_layer (256 blocks, 16 rows each) -------------------
__global__ __launch_bounds__(256) void atom_layer(
    const void* __restrict__ atom,
    const void* __restrict__ alB0, const void* __restrict__ alB1,
    void* __restrict__ out) {
    __shared__ __align__(16) u16 sXF[1 * 8 * 64 * 8];   // 8KB
    __shared__ __align__(16) u16 sHF[1 * 4 * 64 * 8];   // 4KB
    const bool isbf = detect_isbf(atom);
    const int t = threadIdx.x, lane = t & 63, w = t >> 6;
    const int quad = lane >> 4;
    const int r0g = blockIdx.x * 16;
    for (int s = t; s < 8 * 64; s += 256) {
        int lane_s = s & 63, ks = s >> 6;
        int n = lane_s & 15, q = lane_s >> 4;
        int k0 = ks * 32 + q * 8;
        f32x4 f0, f1;
        if (k0 < 128) {
            const float* src = &g_A0[(size_t)(r0g + n) * 128 + k0];
            f0 = *(const f32x4*)src; f1 = *(const f32x4*)(src + 4);
        } else {
            // A1 = sum of the two 32-row partials produced by pair_fused
            const float* s0 = &g_A1[((size_t)(r0g + n) * 2    ) * 128 + (k0 - 128)];
            const float* s1 = &g_A1[((size_t)(r0g + n) * 2 + 1) * 128 + (k0 - 128)];
            f32x4 a0 = *(const f32x4*)s0, a1 = *(const f32x4*)(s0 + 4);
            f32x4 b0 = *(const f32x4*)s1, b1 = *(const f32x4*)(s1 + 4);
#pragma unroll
            for (int r = 0; r < 4; ++r) { f0[r] = a0[r] + b0[r]; f1[r] = a1[r] + b1[r]; }
        }
        uint4 u;
        u.x = f2bf_pk(f0[0], f0[1]); u.y = f2bf_pk(f0[2], f0[3]);
        u.z = f2bf_pk(f1[0], f1[1]); u.w = f2bf_pk(f1[2], f1[3]);
        *(uint4*)&sXF[s * 8] = u;
    }
    __syncthreads();
    const int mt0 = 2 * w;
    {
        f32x4 bb0 = ldf4(alB0, mt0 * 16 + quad * 4, isbf);
        f32x4 bb1 = ldf4(alB0, (mt0 + 1) * 16 + quad * 4, isbf);
        f32x4 acc[2][1];
#pragma unroll
        for (int ii = 0; ii < 2; ++ii) acc[ii][0] = (f32x4){0.f, 0.f, 0.f, 0.f};
        gemm2<8, 1>(g_Wf + OFF_AL0, sXF, mt0, lane, acc);
        EPI_RELU_STORE(acc, bb0, bb1, sHF, 1);
    }
    __syncthreads();
    {
        f32x4 bb0 = ldf4(alB1, mt0 * 16 + quad * 4, isbf);
        f32x4 bb1 = ldf4(alB1, (mt0 + 1) * 16 + quad * 4, isbf);
        f32x4 acc[2][1];
#pragma unroll
        for (int ii = 0; ii < 2; ++ii) acc[ii][0] = (f32x4){0.f, 0.f, 0.f, 0.f};
        gemm2<4, 1>(g_Wf + OFF_AL1, sHF, mt0, lane, acc);
        int c = lane & 15;
#pragma unroll
        for (int ii = 0; ii < 2; ++ii) {
            int mt = mt0 + ii;
            f32x4 bb = ii ? bb1 : bb0;
            f32x4 v;
#pragma unroll
            for (int r = 0; r < 4; ++r) { float x = acc[ii][0][r] + bb[r]; v[r] = x > 0.f ? x : 0.f; }
            store_out4(out, (size_t)(r0g + c) * 128 + mt * 16 + quad * 4, v, isbf);
        }
    }
}

// ---------------- Kernel: fused pair branch + PairToAtom (8192 half-tile blocks) --
// Half-tile: 32 pair-rows per block -> LDS 26KB -> 6 blocks/CU (vs 3 at 52KB).
// Per-CU MFMA/LDS work unchanged; independent block-streams double, which is the
// only variable that moved the needle across R0-R4 (phase chain is latency-bound,
// no pipe >40%).
__global__ __launch_bounds__(256, 6) void pair_fused(
    const void* __restrict__ atom,
    const void* __restrict__ pairx,
    const void* __restrict__ apB0, const void* __restrict__ apB1,
    const void* __restrict__ ppB0, const void* __restrict__ ppB1,
    const void* __restrict__ plB0, const void* __restrict__ plB1,
    const void* __restrict__ paB0, const void* __restrict__ paB1,
    void* __restrict__ out) {
    __shared__ __align__(16) u16 sX1[2 * 4 * 64 * 8];   // 8KB  H0 -> Hp -> Hl
    __shared__ __align__(16) u16 sX2[2 * 4 * 64 * 8];   // 8KB  H1 -> HpA
    __shared__ __align__(16) u16 sR [2 * 4 * 64 * 8];   // 8KB  P0 -> P1
    __shared__ __align__(16) u16 sPr[2 * 1 * 64 * 8];   // 2KB  pair_x frags
    const bool isbf = detect_isbf(atom);
    const int t = threadIdx.x, lane = t & 63, w = t >> 6;
    const int quad = lane >> 4, c = lane & 15;
    const int bx = blockIdx.x;
    const int b = bx >> 7, i = (bx >> 1) & 63, half = bx & 1;
    const int trow = b * 64;
    const int jbase = half * 32;                      // this block's 32 j-rows
    const size_t jrow0 = (size_t)b * 4096 + (size_t)i * 64 + jbase;
    const int mt0 = 2 * w;

    // ---- stage (no barriers yet): Pr frags + H0/H1 built from registers ----
    if (t < 128) {
        int lane_s = t & 63, nt = t >> 6;
        int n = nt * 16 + (lane_s & 15), q = lane_s >> 4;
        *(uint4*)&sPr[t * 8] = pack8(pairx, (jrow0 + n) * FP_, FP_, q * 8, isbf);
    }
    {
        const int ksg = t >> 6;               // this thread's ks segment
        const int k0 = ksg * 32 + quad * 8;   // fixed 8-wide k window
        const int rc = c;                     // row-class within each 16-row group
        const float* TBi = &g_TB[(size_t)(trow + i) * 256 + k0];
        f32x4 t0 = *(const f32x4*)TBi,        t1 = *(const f32x4*)(TBi + 4);
        f32x4 o0 = *(const f32x4*)(TBi + 128), o1 = *(const f32x4*)(TBi + 132);
        f32x4 b0a = ldf4(apB0, k0, isbf), b0b = ldf4(apB0, k0 + 4, isbf);
        float Tip[8], Bip[8];
#pragma unroll
        for (int r = 0; r < 4; ++r) {
            Tip[r] = t0[r] + b0a[r]; Tip[4 + r] = t1[r] + b0b[r];
            Bip[r] = o0[r] + b0a[r]; Bip[4 + r] = o1[r] + b0b[r];
        }
#pragma unroll
        for (int nt = 0; nt < 2; ++nt) {
            int n = jbase + nt * 16 + rc;     // j-row within the (b,i) 64-group
            const float* Bj = &g_TB[(size_t)(trow + n) * 256 + k0];
            f32x4 j0 = *(const f32x4*)Bj,        j1 = *(const f32x4*)(Bj + 4);
            f32x4 j2 = *(const f32x4*)(Bj + 128), j3 = *(const f32x4*)(Bj + 132);
            float v0[8], v1[8];
#pragma unroll
            for (int r = 0; r < 4; ++r) {
                float x0 = Tip[r] + j2[r];      v0[r]     = x0 > 0.f ? x0 : 0.f;  // H0
                float x1 = Tip[4 + r] + j3[r];  v0[4 + r] = x1 > 0.f ? x1 : 0.f;
                float y0 = j0[r] + Bip[r];      v1[r]     = y0 > 0.f ? y0 : 0.f;  // H1
                float y1 = j1[r] + Bip[4 + r];  v1[4 + r] = y1 > 0.f ? y1 : 0.f;
            }
            uint4 u0, u1;
            u0.x = f2bf_pk(v0[0], v0[1]); u0.y = f2bf_pk(v0[2], v0[3]);
            u0.z = f2bf_pk(v0[4], v0[5]); u0.w = f2bf_pk(v0[6], v0[7]);
            u1.x = f2bf_pk(v1[0], v1[1]); u1.y = f2bf_pk(v1[2], v1[3]);
            u1.z = f2bf_pk(v1[4], v1[5]); u1.w = f2bf_pk(v1[6], v1[7]);
            int slot = ((nt * 4 + ksg) * 64 + lane) * 8;
            *(uint4*)&sX1[slot] = u0;
            *(uint4*)&sX2[slot] = u1;
        }
    }
    __syncthreads();
    // ---- phase C: P0 = relu(H0@apW1+b1)+relu(H1@apW1+b1) -> sR ;
    //               aH = Pr@ppW0, aPA = Pr@paW0 (regs, carried across barrier) ----
    {
        f32x4 bb0 = ldf4(apB1, mt0 * 16 + quad * 4, isbf);
        f32x4 bb1 = ldf4(apB1, (mt0 + 1) * 16 + quad * 4, isbf);
        f32x4 aA[2][2], aB[2][2];
#pragma unroll
        for (int ii = 0; ii < 2; ++ii)
#pragma unroll
            for (int nt = 0; nt < 2; ++nt) { aA[ii][nt] = (f32x4){0.f,0.f,0.f,0.f}; aB[ii][nt] = (f32x4){0.f,0.f,0.f,0.f}; }
        gemm2<4, 2>(g_Wf + OFF_AP1, sX1, mt0, lane, aA);
        gemm2<4, 2>(g_Wf + OFF_AP1, sX2, mt0, lane, aB);
#pragma unroll
        for (int ii = 0; ii < 2; ++ii) {
            int mt = mt0 + ii;
            f32x4 bb = ii ? bb1 : bb0;
#pragma unroll
            for (int nt = 0; nt < 2; ++nt) {
                f32x4 v;
#pragma unroll
                for (int r = 0; r < 4; ++r) {
                    float x = aA[ii][nt][r] + bb[r];
                    float y = aB[ii][nt][r] + bb[r];
                    v[r] = (x > 0.f ? x : 0.f) + (y > 0.f ? y : 0.f);
                }
                frag_store(sR, 4, nt, mt, lane, v);
            }
        }
    }
    f32x4 aH[2][2], aPA[2][2];
#pragma unroll
    for (int ii = 0; ii < 2; ++ii)
#pragma unroll
        for (int nt = 0; nt < 2; ++nt) { aH[ii][nt] = (f32x4){0.f,0.f,0.f,0.f}; aPA[ii][nt] = (f32x4){0.f,0.f,0.f,0.f}; }
    gemm2<1, 2>(g_Wf + OFF_PP0, sPr, mt0, lane, aH);
    gemm2<1, 2>(g_Wf + OFF_PA0, sPr, mt0, lane, aPA);
    __syncthreads();
    // ---- phase D: C3 = P0@plW0_top ; Hp = relu(aH+b0p) -> sX1 ; HpA = relu(aPA+b0pa) -> sX2
    f32x4 C3[2][2];
#pragma unroll
    for (int ii = 0; ii < 2; ++ii)
#pragma unroll
        for (int nt = 0; nt < 2; ++nt) C3[ii][nt] = (f32x4){0.f, 0.f, 0.f, 0.f};
    gemm2<4, 2>(g_Wf + OFF_PL0T, sR, mt0, lane, C3);
    {
        f32x4 bb0 = ldf4(ppB0, mt0 * 16 + quad * 4, isbf);
        f32x4 bb1 = ldf4(ppB0, (mt0 + 1) * 16 + quad * 4, isbf);
        EPI_RELU_STORE(aH, bb0, bb1, sX1, 2);
    }
    {
        f32x4 bb0 = ldf4(paB0, mt0 * 16 + quad * 4, isbf);
        f32x4 bb1 = ldf4(paB0, (mt0 + 1) * 16 + quad * 4, isbf);
        EPI_RELU_STORE(aPA, bb0, bb1, sX2, 2);
    }
    __syncthreads();
    // ---- phase E: P1 = relu(Hp@ppW1+b1p) -> sR ;
    //               aA1 = HpA@paW1 -> bias/relu/32-row partial sum -> g_A1 ----
    {
        f32x4 aP[2][2], aA1[2][2];
#pragma unroll
        for (int ii = 0; ii < 2; ++ii)
#pragma unroll
            for (int nt = 0; nt < 2; ++nt) { aP[ii][nt] = (f32x4){0.f,0.f,0.f,0.f}; aA1[ii][nt] = (f32x4){0.f,0.f,0.f,0.f}; }
        gemm2<4, 2>(g_Wf + OFF_PP1, sX1, mt0, lane, aP);
        gemm2<4, 2>(g_Wf + OFF_PA1, sX2, mt0, lane, aA1);
        {
            f32x4 pb0 = ldf4(paB1, mt0 * 16 + quad * 4, isbf);
            f32x4 pb1 = ldf4(paB1, (mt0 + 1) * 16 + quad * 4, isbf);
#pragma unroll
            for (int ii = 0; ii < 2; ++ii) {
                int mt = mt0 + ii;
                f32x4 bb = ii ? pb1 : pb0;
                f32x4 ssum = (f32x4){0.f, 0.f, 0.f, 0.f};
#pragma unroll
                for (int nt = 0; nt < 2; ++nt)
#pragma unroll
                    for (int r = 0; r < 4; ++r) {
                        float x = aA1[ii][nt][r] + bb[r];
                        ssum[r] += (x > 0.f ? x : 0.f);
                    }
#pragma unroll
                for (int m = 1; m < 16; m <<= 1)
#pragma unroll
                    for (int r = 0; r < 4; ++r) ssum[r] += __shfl_xor(ssum[r], m, 64);
                if ((lane & 15) == 0)
                    *(f32x4*)&g_A1[(size_t)bx * 128 + mt * 16 + quad * 4] = ssum;
            }
        }
        f32x4 bb0 = ldf4(ppB1, mt0 * 16 + quad * 4, isbf);
        f32x4 bb1 = ldf4(ppB1, (mt0 + 1) * 16 + quad * 4, isbf);
        EPI_RELU_STORE(aP, bb0, bb1, sR, 2);
    }
    __syncthreads();
    // ---- phase F: C3 += P1@plW0_bot ; Hl = relu(C3 + b0l) -> sX1 ----
    gemm2<4, 2>(g_Wf + OFF_PL0B, sR, mt0, lane, C3);
    {
        f32x4 bb0 = ldf4(plB0, mt0 * 16 + quad * 4, isbf);
        f32x4 bb1 = ldf4(plB0, (mt0 + 1) * 16 + quad * 4, isbf);
        EPI_RELU_STORE(C3, bb0, bb1, sX1, 2);
    }
    __syncthreads();
    // ---- phase G: out = relu(Hl@plW1 + b1l) ----
    {
        f32x4 bb0 = ldf4(plB1, mt0 * 16 + quad * 4, isbf);
        f32x4 bb1 = ldf4(plB1, (mt0 + 1) * 16 + quad * 4, isbf);
        f32x4 aO[2][2];
#pragma unroll
        for (int ii = 0; ii < 2; ++ii)
#pragma unroll
            for (int nt = 0; nt < 2; ++nt) aO[ii][nt] = (f32x4){0.f, 0.f, 0.f, 0.f};
        gemm2<4, 2>(g_Wf + OFF_PL1, sX1, mt0, lane, aO);
        const size_t NA = (size_t)B_ * N_ * C_;   // 524288
#pragma unroll
        for (int ii = 0; ii < 2; ++ii) {
            int mt = mt0 + ii;
            f32x4 bb = ii ? bb1 : bb0;
#pragma unroll
            for (int nt = 0; nt < 2; ++nt) {
                f32x4 v;
#pragma unroll
                for (int r = 0; r < 4; ++r) { float x = aO[ii][nt][r] + bb[r]; v[r] = x > 0.f ? x : 0.f; }
                store_out4(out, NA + (jrow0 + nt * 16 + c) * 128 + mt * 16 + quad * 4, v, isbf);
            }
        }
    }
}

extern "C" void kernel_launch(void* const* d_in, const int* in_sizes, int n_in,
                              void* d_out, int out_size, void* d_ws, size_t ws_size,
                              hipStream_t stream) {
    const void* atom  = d_in[0];
    const void* pairx = d_in[1];
    const void* aaW0 = d_in[2];  const void* aaB0 = d_in[3];
    const void* aaW1 = d_in[4];  const void* aaB1 = d_in[5];
    const void* paW0 = d_in[6];  const void* paB0 = d_in[7];
    const void* paW1 = d_in[8];  const void* paB1 = d_in[9];
    const void* alW0 = d_in[10]; const void* alB0 = d_in[11];
    const void* alW1 = d_in[12]; const void* alB1 = d_in[13];
    const void* apW0 = d_in[14]; const void* apB0 = d_in[15];
    const void* apW1 = d_in[16]; const void* apB1 = d_in[17];
    const void* ppW0 = d_in[18]; const void* ppB0 = d_in[19];
    const void* ppW1 = d_in[20]; const void* ppB1 = d_in[21];
    const void* plW0 = d_in[22]; const void* plB0 = d_in[23];
    const void* plW1 = d_in[24]; const void* plB1 = d_in[25];
    (void)d_ws; (void)ws_size; (void)in_sizes; (void)n_in; (void)out_size;

    prep_w<<<102, 256, 0, stream>>>(atom, aaW0, aaW1, apW0, paW0, paW1, alW0, alW1,
                                    apW1, ppW0, ppW1, plW0, plW1);
    atom_pre<<<128, 256, 0, stream>>>(atom, aaB0, aaB1);
    pair_fused<<<8192, 256, 0, stream>>>(atom, pairx, apB0, apB1, ppB0, ppB1,
                                         plB0, plB1, paB0, paB1, d_out);
    atom_layer<<<256, 256, 0, stream>>>(atom, alB0, alB1, d_out);
}

// Round 6
// 288.877 us; speedup vs baseline: 1.7119x; 1.1296x over previous
//
#include <hip/hip_runtime.h>
#include <hip/hip_bf16.h>

typedef unsigned short u16;
typedef unsigned int u32;
typedef __attribute__((ext_vector_type(8))) __bf16 bf16x8;
typedef __attribute__((ext_vector_type(4))) float f32x4;

#define B_ 64
#define N_ 64
#define FA_ 75
#define FP_ 14
#define C_ 128

// ---- static device scratch (fully rewritten every call) ----
__device__ float g_A0[4096 * 128];   // a0 branch, fp32 [row][feat]
__device__ float g_A1[4096 * 128];   // p2a-summed branch, fp32 (written by pair_fused)
__device__ float g_TB[4096 * 256];   // [T | Bo] per atom row, fp32
__device__ u16   g_Wf[208896];       // all weights in A-fragment layout (bf16)

// frag-weight offsets (u16 elements); layout slot = ((mt*KS+ks)*64+lane)*8+j
#define OFF_AA0   0
#define OFF_AA1   12288
#define OFF_APT   28672
#define OFF_APB   40960
#define OFF_PA0   53248
#define OFF_PA1   57344
#define OFF_AL0   73728
#define OFF_AL1   106496
#define OFF_AP1   122880
#define OFF_PP0   139264
#define OFF_PP1   143360
#define OFF_PL0T  159744
#define OFF_PL0B  176128
#define OFF_PL1   192512

__device__ __forceinline__ float bf2f(u16 a) {
    union { u32 u; float f; } v; v.u = ((u32)a) << 16; return v.f;
}
__device__ __forceinline__ u16 f2bf(float f) {
    union { float f; u32 u; } v; v.f = f;
    u32 r = v.u + 0x7fffu + ((v.u >> 16) & 1u);   // RNE
    return (u16)(r >> 16);
}
#if __has_builtin(__builtin_amdgcn_cvt_pk_bf16_f32)
__device__ __forceinline__ u32 f2bf_pk(float a, float b) {
    auto r = __builtin_amdgcn_cvt_pk_bf16_f32(a, b);
    if constexpr (sizeof(r) == 4) {
        union { decltype(r) v; u32 u; } c; c.v = r; return c.u;
    } else {
        return (u32)f2bf(a) | ((u32)f2bf(b) << 16);
    }
}
#else
__device__ __forceinline__ u32 f2bf_pk(float a, float b) {
    return (u32)f2bf(a) | ((u32)f2bf(b) << 16);
}
#endif

// per-wave input dtype detection: bf16 N(0,1) samples have sane exponents in
// the LOW halfword of each u32; fp32 mantissa bits don't. Uniform per wave.
__device__ __forceinline__ bool detect_isbf(const void* __restrict__ atom) {
    u32 wrd = ((const u32*)atom)[threadIdx.x & 63];
    u32 ex = (wrd >> 7) & 0xffu;
    unsigned long long m = __ballot(ex >= 113u && ex <= 133u);
    return __popcll(m) >= 32;
}

__device__ __forceinline__ float ldf(const void* p, size_t i, bool isbf) {
    if (isbf) return bf2f(((const u16*)p)[i]);
    return ((const float*)p)[i];
}
__device__ __forceinline__ f32x4 ldf4(const void* p, int i, bool isbf) {
    f32x4 r;
    if (isbf) {
        const u16* q = (const u16*)p + i;
        r[0] = bf2f(q[0]); r[1] = bf2f(q[1]); r[2] = bf2f(q[2]); r[3] = bf2f(q[3]);
    } else {
        r = *(const f32x4*)((const float*)p + i);
    }
    return r;
}
// pack 8 row elements k0..k0+7 (zero-padded past kmax) into bf16x8 frag word
__device__ __forceinline__ uint4 pack8(const void* p, size_t base, int kmax, int k0, bool isbf) {
    uint4 u;
    if (isbf) {
        const u16* q = (const u16*)p + base;
        u16 h[8];
#pragma unroll
        for (int j = 0; j < 8; ++j) h[j] = (k0 + j < kmax) ? q[k0 + j] : (u16)0;
        u.x = (u32)h[0] | ((u32)h[1] << 16); u.y = (u32)h[2] | ((u32)h[3] << 16);
        u.z = (u32)h[4] | ((u32)h[5] << 16); u.w = (u32)h[6] | ((u32)h[7] << 16);
    } else {
        const float* q = (const float*)p + base;
        float f[8];
#pragma unroll
        for (int j = 0; j < 8; ++j) f[j] = (k0 + j < kmax) ? q[k0 + j] : 0.f;
        u.x = f2bf_pk(f[0], f[1]); u.y = f2bf_pk(f[2], f[3]);
        u.z = f2bf_pk(f[4], f[5]); u.w = f2bf_pk(f[6], f[7]);
    }
    return u;
}

// ---------------- weight prep: global [K][128] -> A-frag layout ----------------
__global__ __launch_bounds__(256) void prep_w(
    const void* atom,
    const void* aaW0, const void* aaW1, const void* apW0,
    const void* paW0, const void* paW1, const void* alW0, const void* alW1,
    const void* apW1, const void* ppW0, const void* ppW1,
    const void* plW0, const void* plW1) {
    const bool isbf = detect_isbf(atom);
    const void* srcs[14] = {aaW0, aaW1, apW0, apW0, paW0, paW1, alW0, alW1,
                            apW1, ppW0, ppW1, plW0, plW0, plW1};
    const int Ktab[14]  = {75, 128, 75, 75, 14, 128, 256, 128, 128, 14, 128, 128, 128, 128};
    const int KStab[14] = {3, 4, 3, 3, 1, 4, 8, 4, 4, 1, 4, 4, 4, 4};
    const int rofft[14] = {0, 0, 0, 75, 0, 0, 0, 0, 0, 0, 0, 0, 128, 0};
    const int baset[14] = {OFF_AA0, OFF_AA1, OFF_APT, OFF_APB, OFF_PA0, OFF_PA1,
                           OFF_AL0, OFF_AL1, OFF_AP1, OFF_PP0, OFF_PP1,
                           OFF_PL0T, OFF_PL0B, OFF_PL1};
    int gid = blockIdx.x * 256 + threadIdx.x;
    int j = 0, s = gid;
    while (j < 14 && s >= KStab[j] * 512) { s -= KStab[j] * 512; ++j; }
    if (j >= 14) return;
    int lane = s & 63, rest = s >> 6;
    int ks = rest % KStab[j], mt = rest / KStab[j];
    int m = mt * 16 + (lane & 15), q = lane >> 4;
    float f[8];
#pragma unroll
    for (int jj = 0; jj < 8; ++jj) {
        int k = ks * 32 + q * 8 + jj;
        f[jj] = (k < Ktab[j]) ? ldf(srcs[j], (size_t)(rofft[j] + k) * 128 + m, isbf) : 0.f;
    }
    uint4 u;
    u.x = f2bf_pk(f[0], f[1]); u.y = f2bf_pk(f[2], f[3]);
    u.z = f2bf_pk(f[4], f[5]); u.w = f2bf_pk(f[6], f[7]);
    *(uint4*)&g_Wf[(size_t)baset[j] + (size_t)s * 8] = u;
}

// ---------------- MFMA GEMM cores ----------------
__device__ __forceinline__ bf16x8 as_bf(uint4 u) {
    union { uint4 u; bf16x8 b; } cv; cv.u = u; return cv.b;
}
template<int KS, int NT>
__device__ __forceinline__ void gemm2(const u16* __restrict__ wf,
                                      const u16* __restrict__ bF,
                                      int mt0, int lane, f32x4 (&acc)[2][NT]) {
#pragma unroll
    for (int ks = 0; ks < KS; ++ks) {
        bf16x8 a0 = *(const bf16x8*)(wf + (((mt0    ) * KS + ks) * 64 + lane) * 8);
        bf16x8 a1 = *(const bf16x8*)(wf + (((mt0 + 1) * KS + ks) * 64 + lane) * 8);
#pragma unroll
        for (int nt = 0; nt < NT; ++nt) {
            bf16x8 b = *(const bf16x8*)(bF + ((nt * KS + ks) * 64 + lane) * 8);
            acc[0][nt] = __builtin_amdgcn_mfma_f32_16x16x32_bf16(a0, b, acc[0][nt], 0, 0, 0);
            acc[1][nt] = __builtin_amdgcn_mfma_f32_16x16x32_bf16(a1, b, acc[1][nt], 0, 0, 0);
        }
    }
}
// prefetched-A variants (distance-1: loads issued just before the barrier that
// precedes their consuming phase; arrays die right after the gemm).
template<int KS>
__device__ __forceinline__ void loadA2(const u16* __restrict__ wf, int mt0, int lane,
                                       uint4 (&aw)[2][KS]) {
#pragma unroll
    for (int ks = 0; ks < KS; ++ks) {
        aw[0][ks] = *(const uint4*)(wf + (((mt0    ) * KS + ks) * 64 + lane) * 8);
        aw[1][ks] = *(const uint4*)(wf + (((mt0 + 1) * KS + ks) * 64 + lane) * 8);
    }
}
template<int KS, int NT>
__device__ __forceinline__ void gemm2r(const uint4 (&aw)[2][KS],
                                       const u16* __restrict__ bF,
                                       int lane, f32x4 (&acc)[2][NT]) {
#pragma unroll
    for (int ks = 0; ks < KS; ++ks) {
        bf16x8 a0 = as_bf(aw[0][ks]);
        bf16x8 a1 = as_bf(aw[1][ks]);
#pragma unroll
        for (int nt = 0; nt < NT; ++nt) {
            bf16x8 b = *(const bf16x8*)(bF + ((nt * KS + ks) * 64 + lane) * 8);
            acc[0][nt] = __builtin_amdgcn_mfma_f32_16x16x32_bf16(a0, b, acc[0][nt], 0, 0, 0);
            acc[1][nt] = __builtin_amdgcn_mfma_f32_16x16x32_bf16(a1, b, acc[1][nt], 0, 0, 0);
        }
    }
}

// lgkm-only barrier: drains LDS ordering, leaves global loads/stores in flight
// (validated pattern, learn_hip m195-m204). No intra-kernel cross-wave global
// dataflow exists in pair_fused, so vmcnt need not drain at barriers.
__device__ __forceinline__ void barrier_lgkm() {
    asm volatile("s_waitcnt lgkmcnt(0)" ::: "memory");
    __builtin_amdgcn_s_barrier();
    asm volatile("" ::: "memory");
}

// C-frag -> next-layer B-frag store (one uint2 per frag per lane)
__device__ __forceinline__ void frag_store(u16* dstF, int KSd, int nt, int mt, int lane, f32x4 v) {
    int c = lane & 15, quad = lane >> 4;
    int lp = c + 16 * ((2 * mt + (quad >> 1)) & 3);
    int ks = mt >> 1;
    uint2 u; u.x = f2bf_pk(v[0], v[1]); u.y = f2bf_pk(v[2], v[3]);
    *(uint2*)(dstF + (((nt * KSd + ks) * 64 + lp) * 8 + (quad & 1) * 4)) = u;
}

__device__ __forceinline__ void store_out4(void* outp, size_t elem, f32x4 v, bool isbf) {
    if (isbf) {
        uint2 u; u.x = f2bf_pk(v[0], v[1]); u.y = f2bf_pk(v[2], v[3]);
        *(uint2*)((u16*)outp + elem) = u;
    } else {
        *(f32x4*)((float*)outp + elem) = v;
    }
}

#define EPI_RELU_STORE(ACC, BB0, BB1, DST, NTN) do {                             \
    _Pragma("unroll") for (int ii = 0; ii < 2; ++ii) {                           \
        f32x4 bb_ = ii ? (BB1) : (BB0);                                          \
        _Pragma("unroll") for (int nt_ = 0; nt_ < NTN; ++nt_) {                  \
            f32x4 v_;                                                            \
            _Pragma("unroll") for (int r_ = 0; r_ < 4; ++r_) {                   \
                float x_ = ACC[ii][nt_][r_] + bb_[r_];                           \
                v_[r_] = x_ > 0.f ? x_ : 0.f;                                    \
            }                                                                    \
            frag_store(DST, 4, nt_, mt0 + ii, lane, v_);                         \
        }                                                                        \
    }                                                                            \
} while (0)

// ---------------- Kernel: atom branch pre-work (128 blocks, 32 rows each) ---------
__global__ __launch_bounds__(256) void atom_pre(
    const void* __restrict__ atom,
    const void* __restrict__ aaB0, const void* __restrict__ aaB1) {
    __shared__ __align__(16) u16 sXF[2 * 3 * 64 * 8];   // 6KB
    __shared__ __align__(16) u16 sHF[2 * 4 * 64 * 8];   // 8KB
    const bool isbf = detect_isbf(atom);
    const int t = threadIdx.x, lane = t & 63, w = t >> 6;
    const int quad = lane >> 4;
    const int r0g = blockIdx.x * 32;
    for (int s = t; s < 2 * 3 * 64; s += 256) {
        int lane_s = s & 63, rest = s >> 6;
        int ks = rest % 3, nt = rest / 3;
        int n = nt * 16 + (lane_s & 15), q = lane_s >> 4;
        *(uint4*)&sXF[s * 8] = pack8(atom, (size_t)(r0g + n) * FA_, FA_, ks * 32 + q * 8, isbf);
    }
    __syncthreads();
    const int mt0 = 2 * w;
    {
        f32x4 bb0 = ldf4(aaB0, mt0 * 16 + quad * 4, isbf);
        f32x4 bb1 = ldf4(aaB0, (mt0 + 1) * 16 + quad * 4, isbf);
        f32x4 acc[2][2];
#pragma unroll
        for (int ii = 0; ii < 2; ++ii)
#pragma unroll
            for (int nt = 0; nt < 2; ++nt) acc[ii][nt] = (f32x4){0.f, 0.f, 0.f, 0.f};
        gemm2<3, 2>(g_Wf + OFF_AA0, sXF, mt0, lane, acc);
        EPI_RELU_STORE(acc, bb0, bb1, sHF, 2);
    }
    __syncthreads();
    {
        f32x4 bb0 = ldf4(aaB1, mt0 * 16 + quad * 4, isbf);
        f32x4 bb1 = ldf4(aaB1, (mt0 + 1) * 16 + quad * 4, isbf);
        f32x4 acc[2][2];
#pragma unroll
        for (int ii = 0; ii < 2; ++ii)
#pragma unroll
            for (int nt = 0; nt < 2; ++nt) acc[ii][nt] = (f32x4){0.f, 0.f, 0.f, 0.f};
        gemm2<4, 2>(g_Wf + OFF_AA1, sHF, mt0, lane, acc);
        int c = lane & 15;
#pragma unroll
        for (int ii = 0; ii < 2; ++ii) {
            int mt = mt0 + ii;
            f32x4 bb = ii ? bb1 : bb0;
#pragma unroll
            for (int nt = 0; nt < 2; ++nt) {
                f32x4 v;
#pragma unroll
                for (int r = 0; r < 4; ++r) { float x = acc[ii][nt][r] + bb[r]; v[r] = x > 0.f ? x : 0.f; }
                *(f32x4*)&g_A0[(size_t)(r0g + nt * 16 + c) * 128 + mt * 16 + quad * 4] = v;
            }
        }
    }
    {
        f32x4 accT[2][2], accB[2][2];
#pragma unroll
        for (int ii = 0; ii < 2; ++ii)
#pragma unroll
            for (int nt = 0; nt < 2; ++nt) { accT[ii][nt] = (f32x4){0.f,0.f,0.f,0.f}; accB[ii][nt] = (f32x4){0.f,0.f,0.f,0.f}; }
        gemm2<3, 2>(g_Wf + OFF_APT, sXF, mt0, lane, accT);
        gemm2<3, 2>(g_Wf + OFF_APB, sXF, mt0, lane, accB);
        int c = lane & 15;
#pragma unroll
        for (int ii = 0; ii < 2; ++ii) {
            int mt = mt0 + ii;
#pragma unroll
            for (int nt = 0; nt < 2; ++nt) {
                size_t row = (size_t)(r0g + nt * 16 + c);
                *(f32x4*)&g_TB[row * 256 + mt * 16 + quad * 4] = accT[ii][nt];
                *(f32x4*)&g_TB[row * 256 + 128 + mt * 16 + quad * 4] = accB[ii][nt];
            }
        }
    }
}

// ---------------- Kernel: atom_layer (256 blocks, 16 rows each) -------------------
__global__ __launch_bounds__(256) void atom_layer(
    const void* __restrict__ atom,
    const void* __restrict__ alB0, const void* __restrict__ alB1,
    void* __restrict__ out) {
    __shared__ __align__(16) u16 sXF[1 * 8 * 64 * 8];   // 8KB
    __shared__ __align__(16) u16 sHF[1 * 4 * 64 * 8];   // 4KB
    const bool isbf = detect_isbf(atom);
    const int t = threadIdx.x, lane = t & 63, w = t >> 6;
    const int quad = lane >> 4;
    const int r0g = blockIdx.x * 16;
    for (int s = t; s < 8 * 64; s += 256) {
        int lane_s = s & 63, ks = s >> 6;
        int n = lane_s & 15, q = lane_s >> 4;
        int k0 = ks * 32 + q * 8;
        const float* src = (k0 < 128) ? &g_A0[(size_t)(r0g + n) * 128 + k0]
                                      : &g_A1[(size_t)(r0g + n) * 128 + (k0 - 128)];
        f32x4 f0 = *(const f32x4*)src, f1 = *(const f32x4*)(src + 4);
        uint4 u;
        u.x = f2bf_pk(f0[0], f0[1]); u.y = f2bf_pk(f0[2], f0[3]);
        u.z = f2bf_pk(f1[0], f1[1]); u.w = f2bf_pk(f1[2], f1[3]);
        *(uint4*)&sXF[s * 8] = u;
    }
    __syncthreads();
    const int mt0 = 2 * w;
    {
        f32x4 bb0 = ldf4(alB0, mt0 * 16 + quad * 4, isbf);
        f32x4 bb1 = ldf4(alB0, (mt0 + 1) * 16 + quad * 4, isbf);
        f32x4 acc[2][1];
#pragma unroll
        for (int ii = 0; ii < 2; ++ii) acc[ii][0] = (f32x4){0.f, 0.f, 0.f, 0.f};
        gemm2<8, 1>(g_Wf + OFF_AL0, sXF, mt0, lane, acc);
        EPI_RELU_STORE(acc, bb0, bb1, sHF, 1);
    }
    __syncthreads();
    {
        f32x4 bb0 = ldf4(alB1, mt0 * 16 + quad * 4, isbf);
        f32x4 bb1 = ldf4(alB1, (mt0 + 1) * 16 + quad * 4, isbf);
        f32x4 acc[2][1];
#pragma unroll
        for (int ii = 0; ii < 2; ++ii) acc[ii][0] = (f32x4){0.f, 0.f, 0.f, 0.f};
        gemm2<4, 1>(g_Wf + OFF_AL1, sHF, mt0, lane, acc);
        int c = lane & 15;
#pragma unroll
        for (int ii = 0; ii < 2; ++ii) {
            int mt = mt0 + ii;
            f32x4 bb = ii ? bb1 : bb0;
            f32x4 v;
#pragma unroll
            for (int r = 0; r < 4; ++r) { float x = acc[ii][0][r] + bb[r]; v[r] = x > 0.f ? x : 0.f; }
            store_out4(out, (size_t)(r0g + c) * 128 + mt * 16 + quad * 4, v, isbf);
        }
    }
}

// ---------------- Kernel: fused pair branch + PairToAtom (4096 blocks) ------------
// Round-0 structure + two targeted changes (R3/R5 showed occupancy is not the
// limiter; the stall is synchronized at phase boundaries):
//   1. lgkm-only barriers (global stores/loads stay in flight across barriers)
//   2. distance-1 weight-frag prefetch: each phase's A-frags are loaded just
//      BEFORE the preceding barrier, so L2 latency overlaps the barrier.
__global__ __launch_bounds__(256, 3) void pair_fused(
    const void* __restrict__ atom,
    const void* __restrict__ pairx,
    const void* __restrict__ apB0, const void* __restrict__ apB1,
    const void* __restrict__ ppB0, const void* __restrict__ ppB1,
    const void* __restrict__ plB0, const void* __restrict__ plB1,
    const void* __restrict__ paB0, const void* __restrict__ paB1,
    void* __restrict__ out) {
    __shared__ __align__(16) u16 sX1[4 * 4 * 64 * 8];   // 16KB  H0 -> Hp -> Hl
    __shared__ __align__(16) u16 sX2[4 * 4 * 64 * 8];   // 16KB  H1 -> HpA
    __shared__ __align__(16) u16 sR [4 * 4 * 64 * 8];   // 16KB  P0 -> P1
    __shared__ __align__(16) u16 sPr[4 * 1 * 64 * 8];   // 4KB   pair_x frags
    const bool isbf = detect_isbf(atom);
    const int t = threadIdx.x, lane = t & 63, w = t >> 6;
    const int quad = lane >> 4, c = lane & 15;
    const int bx = blockIdx.x;
    const int b = bx >> 6, i = bx & 63;
    const int trow = b * 64;
    const size_t prow0 = (size_t)b * 4096 + (size_t)i * 64;
    const int mt0 = 2 * w;

    // ---- stage (no barriers yet): Pr frags + H0/H1 built from registers ----
    {
        int lane_s = t & 63, nt = t >> 6;
        int n = nt * 16 + (lane_s & 15), q = lane_s >> 4;
        *(uint4*)&sPr[t * 8] = pack8(pairx, (prow0 + n) * FP_, FP_, q * 8, isbf);
    }
    {
        const int ksg = t >> 6;               // this thread's ks segment
        const int k0 = ksg * 32 + quad * 8;   // fixed 8-wide k window
        const int rc = c;                     // row-class within each 16-row group
        const float* TBi = &g_TB[(size_t)(trow + i) * 256 + k0];
        f32x4 t0 = *(const f32x4*)TBi,        t1 = *(const f32x4*)(TBi + 4);
        f32x4 o0 = *(const f32x4*)(TBi + 128), o1 = *(const f32x4*)(TBi + 132);
        f32x4 b0a = ldf4(apB0, k0, isbf), b0b = ldf4(apB0, k0 + 4, isbf);
        float Tip[8], Bip[8];
#pragma unroll
        for (int r = 0; r < 4; ++r) {
            Tip[r] = t0[r] + b0a[r]; Tip[4 + r] = t1[r] + b0b[r];
            Bip[r] = o0[r] + b0a[r]; Bip[4 + r] = o1[r] + b0b[r];
        }
#pragma unroll
        for (int nt = 0; nt < 4; ++nt) {
            int n = nt * 16 + rc;
            const float* Bj = &g_TB[(size_t)(trow + n) * 256 + k0];
            f32x4 j0 = *(const f32x4*)Bj,        j1 = *(const f32x4*)(Bj + 4);
            f32x4 j2 = *(const f32x4*)(Bj + 128), j3 = *(const f32x4*)(Bj + 132);
            float v0[8], v1[8];
#pragma unroll
            for (int r = 0; r < 4; ++r) {
                float x0 = Tip[r] + j2[r];      v0[r]     = x0 > 0.f ? x0 : 0.f;  // H0
                float x1 = Tip[4 + r] + j3[r];  v0[4 + r] = x1 > 0.f ? x1 : 0.f;
                float y0 = j0[r] + Bip[r];      v1[r]     = y0 > 0.f ? y0 : 0.f;  // H1
                float y1 = j1[r] + Bip[4 + r];  v1[4 + r] = y1 > 0.f ? y1 : 0.f;
            }
            uint4 u0, u1;
            u0.x = f2bf_pk(v0[0], v0[1]); u0.y = f2bf_pk(v0[2], v0[3]);
            u0.z = f2bf_pk(v0[4], v0[5]); u0.w = f2bf_pk(v0[6], v0[7]);
            u1.x = f2bf_pk(v1[0], v1[1]); u1.y = f2bf_pk(v1[2], v1[3]);
            u1.z = f2bf_pk(v1[4], v1[5]); u1.w = f2bf_pk(v1[6], v1[7]);
            int slot = ((nt * 4 + ksg) * 64 + lane) * 8;
            *(uint4*)&sX1[slot] = u0;
            *(uint4*)&sX2[slot] = u1;
        }
    }
    // prefetch phase-C weights (independent of LDS; overlaps barrier)
    uint4 aAP1[2][4]; loadA2<4>(g_Wf + OFF_AP1, mt0, lane, aAP1);
    barrier_lgkm();
    // ---- phase C: P0 = relu(H0@apW1+b1)+relu(H1@apW1+b1) -> sR ;
    //               aH = Pr@ppW0, aPA = Pr@paW0 (regs, carried across barrier) ----
    {
        f32x4 bb0 = ldf4(apB1, mt0 * 16 + quad * 4, isbf);
        f32x4 bb1 = ldf4(apB1, (mt0 + 1) * 16 + quad * 4, isbf);
        f32x4 aA[2][4], aB[2][4];
#pragma unroll
        for (int ii = 0; ii < 2; ++ii)
#pragma unroll
            for (int nt = 0; nt < 4; ++nt) { aA[ii][nt] = (f32x4){0.f,0.f,0.f,0.f}; aB[ii][nt] = (f32x4){0.f,0.f,0.f,0.f}; }
        gemm2r<4, 4>(aAP1, sX1, lane, aA);
        gemm2r<4, 4>(aAP1, sX2, lane, aB);
#pragma unroll
        for (int ii = 0; ii < 2; ++ii) {
            int mt = mt0 + ii;
            f32x4 bb = ii ? bb1 : bb0;
#pragma unroll
            for (int nt = 0; nt < 4; ++nt) {
                f32x4 v;
#pragma unroll
                for (int r = 0; r < 4; ++r) {
                    float x = aA[ii][nt][r] + bb[r];
                    float y = aB[ii][nt][r] + bb[r];
                    v[r] = (x > 0.f ? x : 0.f) + (y > 0.f ? y : 0.f);
                }
                frag_store(sR, 4, nt, mt, lane, v);
            }
        }
    }
    f32x4 aH[2][4], aPA[2][4];
    {
        uint4 aPP0[2][1]; loadA2<1>(g_Wf + OFF_PP0, mt0, lane, aPP0);
        uint4 aPA0[2][1]; loadA2<1>(g_Wf + OFF_PA0, mt0, lane, aPA0);
#pragma unroll
        for (int ii = 0; ii < 2; ++ii)
#pragma unroll
            for (int nt = 0; nt < 4; ++nt) { aH[ii][nt] = (f32x4){0.f,0.f,0.f,0.f}; aPA[ii][nt] = (f32x4){0.f,0.f,0.f,0.f}; }
        gemm2r<1, 4>(aPP0, sPr, lane, aH);
        gemm2r<1, 4>(aPA0, sPr, lane, aPA);
    }
    // prefetch phase-D weights
    uint4 aPL0T[2][4]; loadA2<4>(g_Wf + OFF_PL0T, mt0, lane, aPL0T);
    barrier_lgkm();
    // ---- phase D: C3 = P0@plW0_top ; Hp = relu(aH+b0p) -> sX1 ; HpA = relu(aPA+b0pa) -> sX2
    f32x4 C3[2][4];
#pragma unroll
    for (int ii = 0; ii < 2; ++ii)
#pragma unroll
        for (int nt = 0; nt < 4; ++nt) C3[ii][nt] = (f32x4){0.f, 0.f, 0.f, 0.f};
    gemm2r<4, 4>(aPL0T, sR, lane, C3);
    {
        f32x4 bb0 = ldf4(ppB0, mt0 * 16 + quad * 4, isbf);
        f32x4 bb1 = ldf4(ppB0, (mt0 + 1) * 16 + quad * 4, isbf);
        EPI_RELU_STORE(aH, bb0, bb1, sX1, 4);
    }
    {
        f32x4 bb0 = ldf4(paB0, mt0 * 16 + quad * 4, isbf);
        f32x4 bb1 = ldf4(paB0, (mt0 + 1) * 16 + quad * 4, isbf);
        EPI_RELU_STORE(aPA, bb0, bb1, sX2, 4);
    }
    // prefetch phase-E weights (peak live: C3 + aPP1 + aPA1 ~ 96 regs)
    uint4 aPP1[2][4]; loadA2<4>(g_Wf + OFF_PP1, mt0, lane, aPP1);
    uint4 aPA1[2][4]; loadA2<4>(g_Wf + OFF_PA1, mt0, lane, aPA1);
    barrier_lgkm();
    // ---- phase E: P1 = relu(Hp@ppW1+b1p) -> sR ;
    //               aA1 = HpA@paW1 -> bias/relu/sum over rows -> g_A1 ----
    {
        f32x4 aP[2][4], aA1[2][4];
#pragma unroll
        for (int ii = 0; ii < 2; ++ii)
#pragma unroll
            for (int nt = 0; nt < 4; ++nt) { aP[ii][nt] = (f32x4){0.f,0.f,0.f,0.f}; aA1[ii][nt] = (f32x4){0.f,0.f,0.f,0.f}; }
        gemm2r<4, 4>(aPP1, sX1, lane, aP);
        gemm2r<4, 4>(aPA1, sX2, lane, aA1);
        {
            f32x4 pb0 = ldf4(paB1, mt0 * 16 + quad * 4, isbf);
            f32x4 pb1 = ldf4(paB1, (mt0 + 1) * 16 + quad * 4, isbf);
#pragma unroll
            for (int ii = 0; ii < 2; ++ii) {
                int mt = mt0 + ii;
                f32x4 bb = ii ? pb1 : pb0;
                f32x4 ssum = (f32x4){0.f, 0.f, 0.f, 0.f};
#pragma unroll
                for (int nt = 0; nt < 4; ++nt)
#pragma unroll
                    for (int r = 0; r < 4; ++r) {
                        float x = aA1[ii][nt][r] + bb[r];
                        ssum[r] += (x > 0.f ? x : 0.f);
                    }
#pragma unroll
                for (int m = 1; m < 16; m <<= 1)
#pragma unroll
                    for (int r = 0; r < 4; ++r) ssum[r] += __shfl_xor(ssum[r], m, 64);
                if ((lane & 15) == 0)
                    *(f32x4*)&g_A1[(size_t)bx * 128 + mt * 16 + quad * 4] = ssum;
            }
        }
        f32x4 bb0 = ldf4(ppB1, mt0 * 16 + quad * 4, isbf);
        f32x4 bb1 = ldf4(ppB1, (mt0 + 1) * 16 + quad * 4, isbf);
        EPI_RELU_STORE(aP, bb0, bb1, sR, 4);
    }
    // prefetch phase-F weights
    uint4 aPL0B[2][4]; loadA2<4>(g_Wf + OFF_PL0B, mt0, lane, aPL0B);
    barrier_lgkm();
    // ---- phase F: C3 += P1@plW0_bot ; Hl = relu(C3 + b0l) -> sX1 ----
    gemm2r<4, 4>(aPL0B, sR, lane, C3);
    {
        f32x4 bb0 = ldf4(plB0, mt0 * 16 + quad * 4, isbf);
        f32x4 bb1 = ldf4(plB0, (mt0 + 1) * 16 + quad * 4, isbf);
        EPI_RELU_STORE(C3, bb0, bb1, sX1, 4);
    }
    // prefetch phase-G weights
    uint4 aPL1[2][4]; loadA2<4>(g_Wf + OFF_PL1, mt0, lane, aPL1);
    barrier_lgkm();
    // ---- phase G: out = relu(Hl@plW1 + b1l) ----
    {
        f32x4 bb0 = ldf4(plB1, mt0 * 16 + quad * 4, isbf);
        f32x4 bb1 = ldf4(plB1, (mt0 + 1) * 16 + quad * 4, isbf);
        f32x4 aO[2][4];
#pragma unroll
        for (int ii = 0; ii < 2; ++ii)
#pragma unroll
            for (int nt = 0; nt < 4; ++nt) aO[ii][nt] = (f32x4){0.f, 0.f, 0.f, 0.f};
        gemm2r<4, 4>(aPL1, sX1, lane, aO);
        const size_t NA = (size_t)B_ * N_ * C_;   // 524288
#pragma unroll
        for (int ii = 0; ii < 2; ++ii) {
            int mt = mt0 + ii;
            f32x4 bb = ii ? bb1 : bb0;
#pragma unroll
            for (int nt = 0; nt < 4; ++nt) {
                f32x4 v;
#pragma unroll
                for (int r = 0; r < 4; ++r) { float x = aO[ii][nt][r] + bb[r]; v[r] = x > 0.f ? x : 0.f; }
                store_out4(out, NA + (prow0 + nt * 16 + c) * 128 + mt * 16 + quad * 4, v, isbf);
            }
        }
    }
}

extern "C" void kernel_launch(void* const* d_in, const int* in_sizes, int n_in,
                              void* d_out, int out_size, void* d_ws, size_t ws_size,
                              hipStream_t stream) {
    const void* atom  = d_in[0];
    const void* pairx = d_in[1];
    const void* aaW0 = d_in[2];  const void* aaB0 = d_in[3];
    const void* aaW1 = d_in[4];  const void* aaB1 = d_in[5];
    const void* paW0 = d_in[6];  const void* paB0 = d_in[7];
    const void* paW1 = d_in[8];  const void* paB1 = d_in[9];
    const void* alW0 = d_in[10]; const void* alB0 = d_in[11];
    const void* alW1 = d_in[12]; const void* alB1 = d_in[13];
    const void* apW0 = d_in[14]; const void* apB0 = d_in[15];
    const void* apW1 = d_in[16]; const void* apB1 = d_in[17];
    const void* ppW0 = d_in[18]; const void* ppB0 = d_in[19];
    const void* ppW1 = d_in[20]; const void* ppB1 = d_in[21];
    const void* plW0 = d_in[22]; const void* plB0 = d_in[23];
    const void* plW1 = d_in[24]; const void* plB1 = d_in[25];
    (void)d_ws; (void)ws_size; (void)in_sizes; (void)n_in; (void)out_size;

    prep_w<<<102, 256, 0, stream>>>(atom, aaW0, aaW1, apW0, paW0, paW1, alW0, alW1,
                                    apW1, ppW0, ppW1, plW0, plW1);
    atom_pre<<<128, 256, 0, stream>>>(atom, aaB0, aaB1);
    pair_fused<<<4096, 256, 0, stream>>>(atom, pairx, apB0, apB1, ppB0, ppB1,
                                         plB0, plB1, paB0, paB1, d_out);
    atom_layer<<<256, 256, 0, stream>>>(atom, alB0, alB1, d_out);
}